// Round 2
// baseline (552.402 us; speedup 1.0000x reference)
//
#include <hip/hip_runtime.h>
#include <stdint.h>

// Problem constants: B=2, T=2048, C=2048, H=16, D=128
#define TSEQ 2048

typedef __bf16 bf16x8 __attribute__((ext_vector_type(8)));
typedef float f32x4 __attribute__((ext_vector_type(4)));

typedef const __attribute__((address_space(1))) unsigned int* gas_u32;
typedef __attribute__((address_space(3))) unsigned int* las_u32;

__device__ __forceinline__ f32x4 mfma16(bf16x8 a, bf16x8 b, f32x4 c) {
  return __builtin_amdgcn_mfma_f32_16x16x32_bf16(a, b, c, 0, 0, 0);
}

// fp32 -> bf16 round-to-nearest-even (values are finite; no NaN path needed)
__device__ __forceinline__ unsigned short f2b(float f) {
  unsigned int u = __float_as_uint(f);
  u += 0x7fffu + ((u >> 16) & 1u);
  return (unsigned short)(u >> 16);
}

// async global->LDS, 16B per lane. LDS dest must be wave-uniform base + lane*16.
__device__ __forceinline__ void gload_lds16(const unsigned short* g, unsigned short* l) {
  __builtin_amdgcn_global_load_lds((gas_u32)(const void*)g, (las_u32)(void*)l, 16, 0, 0);
}

// ---------------- cast fp32 -> bf16 (vectorized, exact-size grid) ----------------
__global__ __launch_bounds__(256) void cast_bf16_kernel(const float* __restrict__ src,
                                                        unsigned short* __restrict__ dst) {
  size_t i = ((size_t)blockIdx.x * 256 + threadIdx.x) * 4;
  float4 v = *(const float4*)(src + i);
  ushort4 o;
  o.x = f2b(v.x); o.y = f2b(v.y); o.z = f2b(v.z); o.w = f2b(v.w);
  *(ushort4*)(dst + i) = o;
}

// ---------------- cast + transpose: src (R x Cc) fp32 -> dst (Cc x R) bf16 ----------------
__global__ __launch_bounds__(256) void transpose_cast_kernel(const float* __restrict__ src,
                                                             unsigned short* __restrict__ dst,
                                                             int R, int Cc) {
  __shared__ float tile[64][65];
  int cb = blockIdx.x * 64;
  int rb = blockIdx.y * 64;
  int t = threadIdx.x;
  int tr = t >> 4;          // 0..15
  int tc = (t & 15) * 4;    // 0..60
#pragma unroll
  for (int i = 0; i < 4; i++) {
    int r = tr + 16 * i;
    float4 v = *(const float4*)(src + (size_t)(rb + r) * Cc + cb + tc);
    tile[r][tc + 0] = v.x; tile[r][tc + 1] = v.y;
    tile[r][tc + 2] = v.z; tile[r][tc + 3] = v.w;
  }
  __syncthreads();
#pragma unroll
  for (int i = 0; i < 4; i++) {
    int r2 = tr + 16 * i;   // dst row = src col
    ushort4 o;
    o.x = f2b(tile[tc + 0][r2]);
    o.y = f2b(tile[tc + 1][r2]);
    o.z = f2b(tile[tc + 2][r2]);
    o.w = f2b(tile[tc + 3][r2]);
    *(ushort4*)(dst + (size_t)(cb + r2) * R + rb + tc) = o;
  }
}

// ---------------- GEMM core: 128x256 tile, BK=64, ring-of-3 LDS, counted vmcnt ----------------
// K-SPLIT wave decomposition: 8 waves = output grid 2(M)x2(N) x 2(K-halves).
// Wave w: wloc=w&3 -> (wm,wn) in {0,64}x{0,128}; ks=w>>2 -> K-half of each BK=64 tile.
// Per-wave output 64x128 partial (acc[4][8]); per K-tile: 12 ds_read_b128 (4A+8B) feed
// 32 MFMAs = 384 B per 16kFLOP MFMA (m201 ratio; the old 64x64 waves were 512 B/MFMA,
// which made the kernel LDS-read-bound at ~38% MfmaUtil). Partial accs of wave pairs
// (w, w^4) are merged through LDS once after the K-loop (~2% of block time).
//
// Schedule invariants (unchanged from the verified ring):
//  - while computing tile t from slot t%3, the 6 global_load_lds for tile t+2 go into
//    slot (t-1)%3, whose last ds_reads completed before this tile's pre-barrier lgkmcnt(0).
//  - raw s_barrier preceded by "s_waitcnt vmcnt(6) lgkmcnt(0)": retires exactly tile t's
//    6 loads; tile t+1's 6 stay in flight ACROSS the barrier. Last iter waits vmcnt(0).
//  - bank conflicts: 128B rows; 16B chunk q of row r lives at slot q ^ (r&7); stage
//    pre-swizzles the GLOBAL source (LDS dest linear), reads apply the same involution.
// After return: acc holds the MERGED result in rows keep0..keep0+1 (see keep0 below);
// core ends with a barrier but callers reusing sm for epilogue staging must sync again.
__device__ __forceinline__ void gemm_core_256(const unsigned short* __restrict__ A,
                                              const unsigned short* __restrict__ Bt,
                                              int K, int bm, int bn,
                                              unsigned short* sm,
                                              f32x4 (&acc)[4][8]) {
  const int t = threadIdx.x;
  const int lane = t & 63, w = t >> 6;
  const int wloc = w & 3;
  const int wm = (wloc >> 1) * 64;       // 0 or 64
  const int wn = (wloc & 1) * 128;       // 0 or 128
  const int ks = w >> 2;                 // K-half of each BK=64 tile
  const int quad = lane >> 4, l16 = lane & 15;
  const int rsw = l16 & 7;               // == row&7 for all frag rows this lane touches
  const int ch = ((ks * 4 + quad) ^ rsw) * 8;  // swizzled chunk offset (shorts) in 64-short row

  // staging: thread handles LDS 16B-chunks {t, t+512(, t+1024, t+1536 for B)};
  // chunk u: row = u>>3, slot = u&7, global chunk = slot ^ (row&7). row+64 keeps row&7.
  const int srow = t >> 3;               // 0..63
  const int gch = (t & 7) ^ (srow & 7);
  const unsigned short* pA = A + (size_t)(bm + srow) * K + gch * 8;
  const unsigned short* pB = Bt + (size_t)(bn + srow) * K + gch * 8;
  const size_t K64 = (size_t)64 * K;

  auto stageA = [&](int k0, unsigned short* dstSlot) {
    gload_lds16(pA + k0, dstSlot + t * 8);
    gload_lds16(pA + K64 + k0, dstSlot + (t + 512) * 8);
  };
  auto stageB01 = [&](int k0, unsigned short* dstSlot) {
    unsigned short* tB = dstSlot + 8192;
    gload_lds16(pB + k0, tB + t * 8);
    gload_lds16(pB + K64 + k0, tB + (t + 512) * 8);
  };
  auto stageB23 = [&](int k0, unsigned short* dstSlot) {
    unsigned short* tB = dstSlot + 8192;
    gload_lds16(pB + 2 * K64 + k0, tB + (t + 1024) * 8);
    gload_lds16(pB + 3 * K64 + k0, tB + (t + 1536) * 8);
  };

  // prologue: stage tiles 0 and 1 (6 loads each)
  stageA(0, sm);          stageB01(0, sm);          stageB23(0, sm);
  stageA(64, sm + 24576); stageB01(64, sm + 24576); stageB23(64, sm + 24576);

  const int nIter = K >> 6;   // 32
  int scur = 0, sstg = 2;

#pragma unroll 1
  for (int it = 0; it < nIter; it++) {
    if (it + 1 < nIter)
      asm volatile("s_waitcnt vmcnt(6) lgkmcnt(0)" ::: "memory");
    else
      asm volatile("s_waitcnt vmcnt(0) lgkmcnt(0)" ::: "memory");
    __builtin_amdgcn_s_barrier();
    asm volatile("" ::: "memory");

    const unsigned short* sA = sm + scur * 24576;
    const unsigned short* sB = sA + 8192;
    unsigned short* tgt = sm + sstg * 24576;
    const bool doStage = (it + 2 < nIter);
    const int k2 = (it + 2) << 6;

    bf16x8 aF[4], bF[8];

    auto mm = [&](int jb) {   // 8 MFMAs: all 4 m-frags x 2 n-frags
      __builtin_amdgcn_s_setprio(1);
#pragma unroll
      for (int i = 0; i < 4; i++)
#pragma unroll
        for (int j2 = 0; j2 < 2; j2++)
          acc[i][jb + j2] = mfma16(aF[i], bF[jb + j2], acc[i][jb + j2]);
      __builtin_amdgcn_s_setprio(0);
    };

    // ph0: A-frags + B[0..1]; stage A of tile t+2
#pragma unroll
    for (int i = 0; i < 4; i++)
      aF[i] = *(const bf16x8*)(sA + (wm + i * 16 + l16) * 64 + ch);
#pragma unroll
    for (int j = 0; j < 2; j++)
      bF[j] = *(const bf16x8*)(sB + (wn + j * 16 + l16) * 64 + ch);
    if (doStage) stageA(k2, tgt);
    mm(0);
    // ph1: B[2..3]; stage B01
#pragma unroll
    for (int j = 2; j < 4; j++)
      bF[j] = *(const bf16x8*)(sB + (wn + j * 16 + l16) * 64 + ch);
    if (doStage) stageB01(k2, tgt);
    mm(2);
    // ph2: B[4..5]; stage B23
#pragma unroll
    for (int j = 4; j < 6; j++)
      bF[j] = *(const bf16x8*)(sB + (wn + j * 16 + l16) * 64 + ch);
    if (doStage) stageB23(k2, tgt);
    mm(4);
    // ph3: B[6..7]
#pragma unroll
    for (int j = 6; j < 8; j++)
      bF[j] = *(const bf16x8*)(sB + (wn + j * 16 + l16) * 64 + ch);
    mm(6);

    scur = (scur == 2) ? 0 : scur + 1;
    sstg = (sstg == 2) ? 0 : sstg + 1;
  }
  __syncthreads();   // all ds_reads of ring done; mbuf below may overwrite slots

  // K-split merge: pair (w, w^4) shares (wm,wn); each gives away half its m-frags.
  // w<4 keeps m-frags 0..1 (rows wm..wm+31), gives 2..3; w>=4 the reverse.
  // Layout per wave: 16 KB at mbuf + w*4096 floats, frag f=(i2*8+j) at f*256 + lane*4
  // (ds_write_b128 / ds_read_b128, lane*16B consecutive -> conflict-free).
  {
    float* mbuf = (float*)sm;
    const int give0 = (w < 4) ? 2 : 0;
    const int keep0 = 2 - give0;
    float* wb = mbuf + w * 4096;
#pragma unroll
    for (int i2 = 0; i2 < 2; i2++)
#pragma unroll
      for (int j = 0; j < 8; j++)
        *(f32x4*)(wb + (i2 * 8 + j) * 256 + lane * 4) = acc[give0 + i2][j];
    __syncthreads();
    const float* pb = mbuf + (w ^ 4) * 4096;
#pragma unroll
    for (int i2 = 0; i2 < 2; i2++)
#pragma unroll
      for (int j = 0; j < 8; j++) {
        f32x4 v = *(const f32x4*)(pb + (i2 * 8 + j) * 256 + lane * 4);
        acc[keep0 + i2][j] += v;
      }
  }
}

// ---------------- GEMM1: qkv = Xb @ Wqkv, fused RoPE epilogue ----------------
// blockIdx.x in [0,24): 256 cols = two adjacent (s,h) head chunks, same s.
// s=0:Q(+scale), 1:K, 2:V(->V^T). After the K-split core, wave w owns rows
// rowbase..rowbase+31 of the tile in acc[keep0..keep0+1][0..7].
// Grid 24x32 = 768 blocks at 1 block/CU (144 KB LDS) = exactly 3.0 scheduling rounds.
__global__ __launch_bounds__(512, 2) void gemm_qkv_rope(const unsigned short* __restrict__ Xb,
                                                        const unsigned short* __restrict__ Wqt,
                                                        unsigned short* __restrict__ Qd,
                                                        unsigned short* __restrict__ Kd,
                                                        unsigned short* __restrict__ Vtd) {
  __shared__ unsigned short smem[73728];  // 144 KB: ring 3x48KB | merge buf | epilogue
  f32x4 acc[4][8];
  const f32x4 z = {0.f, 0.f, 0.f, 0.f};
#pragma unroll
  for (int i = 0; i < 4; i++)
#pragma unroll
    for (int j = 0; j < 8; j++) acc[i][j] = z;

  const int bm = blockIdx.y * 128;
  const int bn = blockIdx.x * 256;
  gemm_core_256(Xb, Wqt, 2048, bm, bn, smem, acc);

  const int c0 = blockIdx.x * 2;          // head-chunk pair
  const int s = c0 >> 4;
  const int hA = c0 & 15, hB = (c0 + 1) & 15;
  const int t = threadIdx.x, lane = t & 63, w = t >> 6;
  const int wloc = w & 3;
  const int wm = (wloc >> 1) * 64, wn = (wloc & 1) * 128;
  const int keep0 = (w < 4) ? 0 : 2;
  const int rowbase = wm + (w >> 2) * 32;
  const int quad = lane >> 4, l16 = lane & 15;
  const int bq = bm >> 11;                // batch index (tiles never straddle batches)
  const int tpos0 = bm & (TSEQ - 1);

  __syncthreads();                        // merge reads done; safe to reuse smem
  unsigned short* sC = smem;

  if (s < 2) {
    const float scl = (s == 0) ? 0.08838834764831845f : 1.0f;  // 1/sqrt(128) folded into Q
#pragma unroll
    for (int j = 0; j < 8; j++) {
      int d = wn + j * 16 + l16;
      int dh = d & 127;                                     // dim within head
      float invf = __expf(-(float)(dh >> 1) * 0.14391157f); // ln(10000)/64
#pragma unroll
      for (int i = 0; i < 2; i++) {
#pragma unroll
        for (int r = 0; r < 4; r++) {
          int row = rowbase + i * 16 + quad * 4 + r;   // tile-local tpos
          float ang = (float)(tpos0 + row) * invf;
          float sn, cs;
          __sincosf(ang, &sn, &cs);
          float v = acc[keep0 + i][j][r];
          float p = __shfl_xor(v, 1, 64);  // partner column d^1 (adjacent lane)
          float outv = (d & 1) ? (v * cs + p * sn) : (v * cs - p * sn);
          sC[row * 264 + d] = f2b(outv * scl);
        }
      }
    }
    __syncthreads();
    unsigned short* dst = (s == 0) ? Qd : Kd;
#pragma unroll
    for (int it = 0; it < 8; it++) {
      int u = t + 512 * it;
      int row = u >> 5, cc = u & 31;
      int hl = cc >> 4;
      size_t gb = ((size_t)(bq * 16 + (hl ? hB : hA)) * TSEQ + tpos0 + row) * 128 + (cc & 15) * 8;
      *(uint4*)(dst + gb) = *(const uint4*)(sC + row * 264 + cc * 8);
    }
  } else {
    // V stored transposed (B,H,D,T): stage as sC[d][tpos_local], then 16B stores along T
#pragma unroll
    for (int j = 0; j < 8; j++) {
      int d = wn + j * 16 + l16;
#pragma unroll
      for (int i = 0; i < 2; i++)
#pragma unroll
        for (int r = 0; r < 4; r++) {
          int col = rowbase + i * 16 + quad * 4 + r;
          sC[d * 136 + col] = f2b(acc[keep0 + i][j][r]);
        }
    }
    __syncthreads();
#pragma unroll
    for (int it = 0; it < 8; it++) {
      int u = t + 512 * it;
      int dd = u >> 4, cc = u & 15;
      int hl = dd >> 7, dl = dd & 127;
      size_t gb = ((size_t)(bq * 16 + (hl ? hB : hA)) * 128 + dl) * TSEQ + tpos0 + cc * 8;
      *(uint4*)(Vtd + gb) = *(const uint4*)(sC + dd * 136 + cc * 8);
    }
  }
}

// ---------------- Flash attention v2 (unchanged) ----------------
// Pair-balanced causal schedule: block (pair, bh) handles q-tiles qA=pair, qB=31-pair
// (33 tile-computes per block, K/V tile at each kb loaded ONCE for both tiles).
// Double-buffered K/V in LDS; XOR-swizzled 16B-chunk placement kills the 16-way bank
// conflicts. LDS: 2*(8192+8192) + 4*16*72 = 74752 B -> 2 blocks/CU.
__global__ __launch_bounds__(256, 2) void attn_kernel(const unsigned short* __restrict__ Q,
                                                      const unsigned short* __restrict__ Kmat,
                                                      const unsigned short* __restrict__ Vt,
                                                      unsigned short* __restrict__ Ob) {
  __shared__ unsigned short smem[37376];
  const int pair = blockIdx.x, bh = blockIdx.y;
  const int qA = pair, qB = 31 - pair;
  const int t = threadIdx.x, lane = t & 63, w = t >> 6, quad = lane >> 4, l16 = lane & 15;
  const size_t base = (size_t)bh * TSEQ * 128;
  const unsigned short* Qp = Q + base;
  const unsigned short* Kp = Kmat + base;
  const unsigned short* Vp = Vt + base;
  unsigned short* myP = smem + 32768 + w * 1152;   // 16 x 72 per wave

  bf16x8 aqA[4], aqB[4];
  {
    int qrA = qA * 64 + w * 16 + l16;
    int qrB = qB * 64 + w * 16 + l16;
#pragma unroll
    for (int kk = 0; kk < 4; kk++) {
      aqA[kk] = *(const bf16x8*)(Qp + (size_t)qrA * 128 + kk * 32 + quad * 8);
      aqB[kk] = *(const bf16x8*)(Qp + (size_t)qrB * 128 + kk * 32 + quad * 8);
    }
  }
  const f32x4 z = {0.f, 0.f, 0.f, 0.f};
  f32x4 oA[8], oB[8];
  float mA[4], lA[4], mB[4], lB[4];
#pragma unroll
  for (int dt = 0; dt < 8; dt++) { oA[dt] = z; oB[dt] = z; }
#pragma unroll
  for (int r = 0; r < 4; r++) { mA[r] = -1e30f; lA[r] = 0.f; mB[r] = -1e30f; lB[r] = 0.f; }

  // swizzled K/V tile load: chunk c of row r lives at slot (c ^ (r&7))
  auto load_tiles = [&](int kb, int buf) {
    unsigned short* bK = smem + buf * 16384;
    unsigned short* bV = bK + 8192;
    const unsigned short* Kt = Kp + (size_t)kb * 64 * 128;
#pragma unroll
    for (int i2 = 0; i2 < 4; i2++) {
      int idx = t + 256 * i2;                       // LDS linear 16B-chunk
      int r = idx >> 4, cS = idx & 15;
      int c = cS ^ (r & 7);
      gload_lds16(Kt + r * 128 + c * 8, bK + idx * 8);
    }
#pragma unroll
    for (int i2 = 0; i2 < 4; i2++) {
      int idx = t + 256 * i2;
      int r = idx >> 3, cS = idx & 7;               // r = d index
      int c = cS ^ (r & 7);
      gload_lds16(Vp + (size_t)r * TSEQ + kb * 64 + c * 8, bV + idx * 8);
    }
  };

  auto process = [&](bf16x8 (&aq)[4], f32x4 (&o)[8], float (&mst)[4], float (&lst)[4],
                     int qb, int kb, const unsigned short* bK, const unsigned short* bV) {
    f32x4 S[4];
#pragma unroll
    for (int nt = 0; nt < 4; nt++) {
      f32x4 sacc = z;
#pragma unroll
      for (int kk = 0; kk < 4; kk++) {
        const unsigned short* p =
            bK + (nt * 16 + l16) * 128 + (((kk * 4 + quad) ^ (l16 & 7)) * 8);
        sacc = mfma16(aq[kk], *(const bf16x8*)p, sacc);
      }
      S[nt] = sacc;
    }
    if (kb == qb) {  // diagonal tile: mask key > q
      int qg = qb * 64 + w * 16 + quad * 4;
#pragma unroll
      for (int nt = 0; nt < 4; nt++) {
        int key = kb * 64 + nt * 16 + l16;
#pragma unroll
        for (int r = 0; r < 4; r++)
          if (key > qg + r) S[nt][r] = -1e30f;
      }
    }
    float alpha[4];
#pragma unroll
    for (int r = 0; r < 4; r++) {
      float mx = fmaxf(fmaxf(S[0][r], S[1][r]), fmaxf(S[2][r], S[3][r]));
      mx = fmaxf(mx, __shfl_xor(mx, 1, 64));
      mx = fmaxf(mx, __shfl_xor(mx, 2, 64));
      mx = fmaxf(mx, __shfl_xor(mx, 4, 64));
      mx = fmaxf(mx, __shfl_xor(mx, 8, 64));
      float mnew = fmaxf(mst[r], mx);
      alpha[r] = __expf(mst[r] - mnew);
      mst[r] = mnew;
    }
    float rs[4] = {0.f, 0.f, 0.f, 0.f};
#pragma unroll
    for (int nt = 0; nt < 4; nt++)
#pragma unroll
      for (int r = 0; r < 4; r++) {
        float p = __expf(S[nt][r] - mst[r]);
        S[nt][r] = p;
        rs[r] += p;
      }
#pragma unroll
    for (int r = 0; r < 4; r++) {
      float s4 = rs[r];
      s4 += __shfl_xor(s4, 1, 64);
      s4 += __shfl_xor(s4, 2, 64);
      s4 += __shfl_xor(s4, 4, 64);
      s4 += __shfl_xor(s4, 8, 64);
      lst[r] = lst[r] * alpha[r] + s4;
#pragma unroll
      for (int nt = 0; nt < 4; nt++)
        myP[(quad * 4 + r) * 72 + nt * 16 + l16] = f2b(S[nt][r]);
    }
#pragma unroll
    for (int dt = 0; dt < 8; dt++) {
      f32x4 ov = o[dt];
      ov[0] *= alpha[0]; ov[1] *= alpha[1]; ov[2] *= alpha[2]; ov[3] *= alpha[3];
      o[dt] = ov;
    }
#pragma unroll
    for (int kk = 0; kk < 2; kk++) {
      bf16x8 ap = *(const bf16x8*)(myP + l16 * 72 + kk * 32 + quad * 8);
#pragma unroll
      for (int dt = 0; dt < 8; dt++) {
        const unsigned short* p =
            bV + (dt * 16 + l16) * 64 + (((kk * 4 + quad) ^ (l16 & 7)) * 8);
        o[dt] = mfma16(ap, *(const bf16x8*)p, o[dt]);
      }
    }
  };

  load_tiles(0, 0);
#pragma unroll 1
  for (int kb = 0; kb <= qB; kb++) {
    __syncthreads();                      // drains loads for current buffer
    if (kb < qB) load_tiles(kb + 1, (kb + 1) & 1);  // prefetch overlaps compute below
    const unsigned short* bK = smem + (kb & 1) * 16384;
    const unsigned short* bV = bK + 8192;
    process(aqB, oB, mB, lB, qB, kb, bK, bV);
    if (kb <= qA) process(aqA, oA, mA, lA, qA, kb, bK, bV);
  }

  // epilogue: both tiles -> LDS (stride 136) -> coalesced 16B stores to Ob (b,t,h,d)
  __syncthreads();                        // all waves done reading K/V buffers
  unsigned short* sOA = smem;             // 64 x 136
  unsigned short* sOB = smem + 8704;      // 64 x 136
#pragma unroll
  for (int dt = 0; dt < 8; dt++)
#pragma unroll
    for (int r = 0; r < 4; r++) {
      int row = w * 16 + quad * 4 + r;
      sOA[row * 136 + dt * 16 + l16] = f2b(oA[dt][r] / lA[r]);
      sOB[row * 136 + dt * 16 + l16] = f2b(oB[dt][r] / lB[r]);
    }
  __syncthreads();
  const int b = bh >> 4, h = bh & 15;
#pragma unroll
  for (int it = 0; it < 4; it++) {
    int c = t + 256 * it;
    int row = c >> 4, off = (c & 15) * 8;
    uint4 va = *(const uint4*)(sOA + row * 136 + off);
    *(uint4*)(Ob + (size_t)(b * TSEQ + qA * 64 + row) * 2048 + h * 128 + off) = va;
    uint4 vb = *(const uint4*)(sOB + row * 136 + off);
    *(uint4*)(Ob + (size_t)(b * TSEQ + qB * 64 + row) * 2048 + h * 128 + off) = vb;
  }
}

// ---------------- GEMM2: out = Ob @ W_out, fp32 epilogue ----------------
// Grid 8x32 = 256 blocks at 1 block/CU = exactly 1.0 scheduling round.
__global__ __launch_bounds__(512, 2) void gemm_out_kernel(const unsigned short* __restrict__ Ob,
                                                          const unsigned short* __restrict__ Wot,
                                                          float* __restrict__ Cout) {
  __shared__ unsigned short smem[73728];  // 144 KB ring + merge buf
  f32x4 acc[4][8];
  const f32x4 z = {0.f, 0.f, 0.f, 0.f};
#pragma unroll
  for (int i = 0; i < 4; i++)
#pragma unroll
    for (int j = 0; j < 8; j++) acc[i][j] = z;

  const int bm = blockIdx.y * 128, bn = blockIdx.x * 256;
  gemm_core_256(Ob, Wot, 2048, bm, bn, smem, acc);

  const int t = threadIdx.x, lane = t & 63, w = t >> 6;
  const int wloc = w & 3;
  const int wm = (wloc >> 1) * 64, wn = (wloc & 1) * 128;
  const int keep0 = (w < 4) ? 0 : 2;
  const int rowbase = wm + (w >> 2) * 32;
  const int quad = lane >> 4, l16 = lane & 15;
#pragma unroll
  for (int i = 0; i < 2; i++)
#pragma unroll
    for (int j = 0; j < 8; j++)
#pragma unroll
      for (int r = 0; r < 4; r++) {
        int row = bm + rowbase + i * 16 + quad * 4 + r;
        int col = bn + wn + j * 16 + l16;
        Cout[(size_t)row * 2048 + col] = acc[keep0 + i][j][r];
      }
}

// ---------------- launch ----------------
extern "C" void kernel_launch(void* const* d_in, const int* in_sizes, int n_in,
                              void* d_out, int out_size, void* d_ws, size_t ws_size,
                              hipStream_t stream) {
  (void)in_sizes; (void)n_in; (void)out_size; (void)ws_size;
  const float* x = (const float*)d_in[0];       // (2,2048,2048)
  const float* Wqkv = (const float*)d_in[1];    // (2048,6144)
  const float* Wout = (const float*)d_in[2];    // (2048,2048)
  float* out = (float*)d_out;                   // (2,2048,2048) fp32
  char* ws = (char*)d_ws;

  unsigned short* Xb  = (unsigned short*)(ws);               // 16 MB  (4096x2048 bf16)
  unsigned short* Wqt = (unsigned short*)(ws + 16777216);    // 24 MB  (6144x2048 bf16, W_qkv^T)
  unsigned short* Wot = (unsigned short*)(ws + 41943040);    // 8 MB   (2048x2048 bf16, W_out^T)
  unsigned short* Qd  = (unsigned short*)(ws + 50331648);    // 16 MB  (B,H,T,D)
  unsigned short* Kd  = (unsigned short*)(ws + 67108864);    // 16 MB  (B,H,T,D)
  unsigned short* Vtd = (unsigned short*)(ws + 83886080);    // 16 MB  (B,H,D,T)
  unsigned short* Obf = (unsigned short*)(ws + 100663296);   // 16 MB  (4096x2048 bf16)

  cast_bf16_kernel<<<8192, 256, 0, stream>>>(x, Xb);
  transpose_cast_kernel<<<dim3(96, 32), 256, 0, stream>>>(Wqkv, Wqt, 2048, 6144);
  transpose_cast_kernel<<<dim3(32, 32), 256, 0, stream>>>(Wout, Wot, 2048, 2048);
  gemm_qkv_rope<<<dim3(24, 32), 512, 0, stream>>>(Xb, Wqt, Qd, Kd, Vtd);
  attn_kernel<<<dim3(16, 32), 256, 0, stream>>>(Qd, Kd, Vtd, Obf);
  gemm_out_kernel<<<dim3(8, 32), 512, 0, stream>>>(Obf, Wot, out);
}

// Round 3
// 370.618 us; speedup vs baseline: 1.4905x; 1.4905x over previous
//
#include <hip/hip_runtime.h>
#include <stdint.h>

// Problem constants: B=2, T=2048, C=2048, H=16, D=128
#define TSEQ 2048

typedef __bf16 bf16x8 __attribute__((ext_vector_type(8)));
typedef float f32x4 __attribute__((ext_vector_type(4)));

typedef const __attribute__((address_space(1))) unsigned int* gas_u32;
typedef __attribute__((address_space(3))) unsigned int* las_u32;

__device__ __forceinline__ f32x4 mfma16(bf16x8 a, bf16x8 b, f32x4 c) {
  return __builtin_amdgcn_mfma_f32_16x16x32_bf16(a, b, c, 0, 0, 0);
}

// fp32 -> bf16 round-to-nearest-even (values are finite; no NaN path needed)
__device__ __forceinline__ unsigned short f2b(float f) {
  unsigned int u = __float_as_uint(f);
  u += 0x7fffu + ((u >> 16) & 1u);
  return (unsigned short)(u >> 16);
}

// async global->LDS, 16B per lane. LDS dest must be wave-uniform base + lane*16.
__device__ __forceinline__ void gload_lds16(const unsigned short* g, unsigned short* l) {
  __builtin_amdgcn_global_load_lds((gas_u32)(const void*)g, (las_u32)(void*)l, 16, 0, 0);
}

// ---------------- cast fp32 -> bf16 (vectorized, exact-size grid) ----------------
__global__ __launch_bounds__(256) void cast_bf16_kernel(const float* __restrict__ src,
                                                        unsigned short* __restrict__ dst) {
  size_t i = ((size_t)blockIdx.x * 256 + threadIdx.x) * 4;
  float4 v = *(const float4*)(src + i);
  ushort4 o;
  o.x = f2b(v.x); o.y = f2b(v.y); o.z = f2b(v.z); o.w = f2b(v.w);
  *(ushort4*)(dst + i) = o;
}

// ---------------- cast + transpose: src (R x Cc) fp32 -> dst (Cc x R) bf16 ----------------
__global__ __launch_bounds__(256) void transpose_cast_kernel(const float* __restrict__ src,
                                                             unsigned short* __restrict__ dst,
                                                             int R, int Cc) {
  __shared__ float tile[64][65];
  int cb = blockIdx.x * 64;
  int rb = blockIdx.y * 64;
  int t = threadIdx.x;
  int tr = t >> 4;          // 0..15
  int tc = (t & 15) * 4;    // 0..60
#pragma unroll
  for (int i = 0; i < 4; i++) {
    int r = tr + 16 * i;
    float4 v = *(const float4*)(src + (size_t)(rb + r) * Cc + cb + tc);
    tile[r][tc + 0] = v.x; tile[r][tc + 1] = v.y;
    tile[r][tc + 2] = v.z; tile[r][tc + 3] = v.w;
  }
  __syncthreads();
#pragma unroll
  for (int i = 0; i < 4; i++) {
    int r2 = tr + 16 * i;   // dst row = src col
    ushort4 o;
    o.x = f2b(tile[tc + 0][r2]);
    o.y = f2b(tile[tc + 1][r2]);
    o.z = f2b(tile[tc + 2][r2]);
    o.w = f2b(tile[tc + 3][r2]);
    *(ushort4*)(dst + (size_t)(cb + r2) * R + rb + tc) = o;
  }
}

// ---------------- GEMM core: 128x256 tile, BK=64, ring-of-3 LDS, counted vmcnt ----------------
// K-SPLIT wave decomposition: 8 waves = output grid 2(M)x2(N) x 2(K-halves).
// Wave w: wloc=w&3 -> (wm,wn) in {0,64}x{0,128}; ks=w>>2 -> K-half of each BK=64 tile.
// Per-wave output 64x128 partial (acc[4][8]); per K-tile: 12 ds_read_b128 (4A+8B) feed
// 32 MFMAs = 384 B per 16kFLOP MFMA (the old 64x64 waves were 512 B/MFMA -> LDS-read-
// bound at ~38% MfmaUtil). Partial accs of wave pairs (w, w^4) are merged through LDS
// once after the K-loop.
//
// !! ALL acc indices must be compile-time constants (rule #20): round-2's runtime
// keep0/give0 indexing demoted acc to scratch (WRITE_SIZE 49->540 MB, 2.2x slower).
// The merge is therefore two wave-uniform STATIC branches, and the merged result is
// canonicalized into acc[0..1][0..7] for every wave.
//
// Schedule invariants (unchanged from the verified ring):
//  - while computing tile t from slot t%3, the 6 global_load_lds for tile t+2 go into
//    slot (t-1)%3, whose last ds_reads completed before this tile's pre-barrier lgkmcnt(0).
//  - raw s_barrier preceded by "s_waitcnt vmcnt(6) lgkmcnt(0)": retires exactly tile t's
//    6 loads; tile t+1's 6 stay in flight ACROSS the barrier. Last iter waits vmcnt(0).
//  - bank conflicts: 128B rows; 16B chunk q of row r lives at slot q ^ (r&7); stage
//    pre-swizzles the GLOBAL source (LDS dest linear), reads apply the same involution.
// After return: wave w owns tile rows [wm + (w>>2)*32, +32) x cols [wn, wn+128) in
// acc[0..1][0..7]. Core ends with full merge sync; callers reusing sm must sync again.
__device__ __forceinline__ void gemm_core_256(const unsigned short* __restrict__ A,
                                              const unsigned short* __restrict__ Bt,
                                              int K, int bm, int bn,
                                              unsigned short* sm,
                                              f32x4 (&acc)[4][8]) {
  const int t = threadIdx.x;
  const int lane = t & 63, w = t >> 6;
  const int wloc = w & 3;
  const int wm = (wloc >> 1) * 64;       // 0 or 64
  const int wn = (wloc & 1) * 128;       // 0 or 128
  const int ks = w >> 2;                 // K-half of each BK=64 tile
  const int quad = lane >> 4, l16 = lane & 15;
  const int rsw = l16 & 7;               // == row&7 for all frag rows this lane touches
  const int ch = ((ks * 4 + quad) ^ rsw) * 8;  // swizzled chunk offset (shorts) in 64-short row

  // staging: thread handles LDS 16B-chunks {t, t+512(, t+1024, t+1536 for B)};
  // chunk u: row = u>>3, slot = u&7, global chunk = slot ^ (row&7). row+64 keeps row&7.
  const int srow = t >> 3;               // 0..63
  const int gch = (t & 7) ^ (srow & 7);
  const unsigned short* pA = A + (size_t)(bm + srow) * K + gch * 8;
  const unsigned short* pB = Bt + (size_t)(bn + srow) * K + gch * 8;
  const size_t K64 = (size_t)64 * K;

  auto stageA = [&](int k0, unsigned short* dstSlot) {
    gload_lds16(pA + k0, dstSlot + t * 8);
    gload_lds16(pA + K64 + k0, dstSlot + (t + 512) * 8);
  };
  auto stageB01 = [&](int k0, unsigned short* dstSlot) {
    unsigned short* tB = dstSlot + 8192;
    gload_lds16(pB + k0, tB + t * 8);
    gload_lds16(pB + K64 + k0, tB + (t + 512) * 8);
  };
  auto stageB23 = [&](int k0, unsigned short* dstSlot) {
    unsigned short* tB = dstSlot + 8192;
    gload_lds16(pB + 2 * K64 + k0, tB + (t + 1024) * 8);
    gload_lds16(pB + 3 * K64 + k0, tB + (t + 1536) * 8);
  };

  // prologue: stage tiles 0 and 1 (6 loads each)
  stageA(0, sm);          stageB01(0, sm);          stageB23(0, sm);
  stageA(64, sm + 24576); stageB01(64, sm + 24576); stageB23(64, sm + 24576);

  const int nIter = K >> 6;   // 32
  int scur = 0, sstg = 2;

#pragma unroll 1
  for (int it = 0; it < nIter; it++) {
    if (it + 1 < nIter)
      asm volatile("s_waitcnt vmcnt(6) lgkmcnt(0)" ::: "memory");
    else
      asm volatile("s_waitcnt vmcnt(0) lgkmcnt(0)" ::: "memory");
    __builtin_amdgcn_s_barrier();
    asm volatile("" ::: "memory");

    const unsigned short* sA = sm + scur * 24576;
    const unsigned short* sB = sA + 8192;
    unsigned short* tgt = sm + sstg * 24576;
    const bool doStage = (it + 2 < nIter);
    const int k2 = (it + 2) << 6;

    bf16x8 aF[4], bF[8];

    auto mm = [&](int jb) {   // 8 MFMAs; jb is always a literal -> static after inline
      __builtin_amdgcn_s_setprio(1);
#pragma unroll
      for (int i = 0; i < 4; i++)
#pragma unroll
        for (int j2 = 0; j2 < 2; j2++)
          acc[i][jb + j2] = mfma16(aF[i], bF[jb + j2], acc[i][jb + j2]);
      __builtin_amdgcn_s_setprio(0);
    };

    // ph0: A-frags + B[0..1]; stage A of tile t+2
#pragma unroll
    for (int i = 0; i < 4; i++)
      aF[i] = *(const bf16x8*)(sA + (wm + i * 16 + l16) * 64 + ch);
#pragma unroll
    for (int j = 0; j < 2; j++)
      bF[j] = *(const bf16x8*)(sB + (wn + j * 16 + l16) * 64 + ch);
    if (doStage) stageA(k2, tgt);
    mm(0);
    // ph1: B[2..3]; stage B01
#pragma unroll
    for (int j = 2; j < 4; j++)
      bF[j] = *(const bf16x8*)(sB + (wn + j * 16 + l16) * 64 + ch);
    if (doStage) stageB01(k2, tgt);
    mm(2);
    // ph2: B[4..5]; stage B23
#pragma unroll
    for (int j = 4; j < 6; j++)
      bF[j] = *(const bf16x8*)(sB + (wn + j * 16 + l16) * 64 + ch);
    if (doStage) stageB23(k2, tgt);
    mm(4);
    // ph3: B[6..7]
#pragma unroll
    for (int j = 6; j < 8; j++)
      bF[j] = *(const bf16x8*)(sB + (wn + j * 16 + l16) * 64 + ch);
    mm(6);

    scur = (scur == 2) ? 0 : scur + 1;
    sstg = (sstg == 2) ? 0 : sstg + 1;
  }
  __syncthreads();   // all ds_reads of ring done; mbuf below may overwrite slots

  // K-split merge: pair (w, w^4) shares (wm,wn); each gives away half its m-frags.
  // w<4 keeps m-frags 0..1 (rows wm..wm+31) and gives 2..3; w>=4 the reverse, then
  // canonicalizes its kept frags into slots 0..1. All indices STATIC (rule #20).
  // Layout per wave: 16 KB at mbuf + w*4096 floats, frag f=(i2*8+j) at f*256 + lane*4
  // (ds_write_b128 / ds_read_b128, lane*16B consecutive -> conflict-free).
  {
    float* mbuf = (float*)sm;
    float* wb = mbuf + w * 4096;
    const int lane4 = lane * 4;
    if (w < 4) {
#pragma unroll
      for (int i2 = 0; i2 < 2; i2++)
#pragma unroll
        for (int j = 0; j < 8; j++)
          *(f32x4*)(wb + (i2 * 8 + j) * 256 + lane4) = acc[2 + i2][j];
    } else {
#pragma unroll
      for (int i2 = 0; i2 < 2; i2++)
#pragma unroll
        for (int j = 0; j < 8; j++)
          *(f32x4*)(wb + (i2 * 8 + j) * 256 + lane4) = acc[i2][j];
    }
    __syncthreads();
    const float* pb = mbuf + (w ^ 4) * 4096;
    if (w < 4) {
#pragma unroll
      for (int i2 = 0; i2 < 2; i2++)
#pragma unroll
        for (int j = 0; j < 8; j++)
          acc[i2][j] += *(const f32x4*)(pb + (i2 * 8 + j) * 256 + lane4);
    } else {
#pragma unroll
      for (int i2 = 0; i2 < 2; i2++)
#pragma unroll
        for (int j = 0; j < 8; j++)
          acc[i2][j] = acc[2 + i2][j] + *(const f32x4*)(pb + (i2 * 8 + j) * 256 + lane4);
    }
  }
}

// ---------------- GEMM1: qkv = Xb @ Wqkv, fused RoPE epilogue ----------------
// blockIdx.x in [0,24): 256 cols = two adjacent (s,h) head chunks, same s.
// s=0:Q(+scale), 1:K, 2:V(->V^T). After the K-split core, wave w owns tile rows
// rowbase..rowbase+31 in acc[0..1][0..7] (canonicalized).
// Grid 24x32 = 768 blocks at 1 block/CU (144 KB LDS) = exactly 3.0 scheduling rounds.
__global__ __launch_bounds__(512, 2) void gemm_qkv_rope(const unsigned short* __restrict__ Xb,
                                                        const unsigned short* __restrict__ Wqt,
                                                        unsigned short* __restrict__ Qd,
                                                        unsigned short* __restrict__ Kd,
                                                        unsigned short* __restrict__ Vtd) {
  __shared__ unsigned short smem[73728];  // 144 KB: ring 3x48KB | merge buf | epilogue
  f32x4 acc[4][8];
  const f32x4 z = {0.f, 0.f, 0.f, 0.f};
#pragma unroll
  for (int i = 0; i < 4; i++)
#pragma unroll
    for (int j = 0; j < 8; j++) acc[i][j] = z;

  const int bm = blockIdx.y * 128;
  const int bn = blockIdx.x * 256;
  gemm_core_256(Xb, Wqt, 2048, bm, bn, smem, acc);

  const int c0 = blockIdx.x * 2;          // head-chunk pair
  const int s = c0 >> 4;
  const int hA = c0 & 15, hB = (c0 + 1) & 15;
  const int t = threadIdx.x, lane = t & 63, w = t >> 6;
  const int wloc = w & 3;
  const int wm = (wloc >> 1) * 64, wn = (wloc & 1) * 128;
  const int rowbase = wm + (w >> 2) * 32;
  const int quad = lane >> 4, l16 = lane & 15;
  const int bq = bm >> 11;                // batch index (tiles never straddle batches)
  const int tpos0 = bm & (TSEQ - 1);

  __syncthreads();                        // merge reads done; safe to reuse smem
  unsigned short* sC = smem;

  if (s < 2) {
    const float scl = (s == 0) ? 0.08838834764831845f : 1.0f;  // 1/sqrt(128) folded into Q
#pragma unroll
    for (int j = 0; j < 8; j++) {
      int d = wn + j * 16 + l16;
      int dh = d & 127;                                     // dim within head
      float invf = __expf(-(float)(dh >> 1) * 0.14391157f); // ln(10000)/64
#pragma unroll
      for (int i = 0; i < 2; i++) {
#pragma unroll
        for (int r = 0; r < 4; r++) {
          int row = rowbase + i * 16 + quad * 4 + r;   // tile-local tpos
          float ang = (float)(tpos0 + row) * invf;
          float sn, cs;
          __sincosf(ang, &sn, &cs);
          float v = acc[i][j][r];
          float p = __shfl_xor(v, 1, 64);  // partner column d^1 (adjacent lane)
          float outv = (d & 1) ? (v * cs + p * sn) : (v * cs - p * sn);
          sC[row * 264 + d] = f2b(outv * scl);
        }
      }
    }
    __syncthreads();
    unsigned short* dst = (s == 0) ? Qd : Kd;
#pragma unroll
    for (int it = 0; it < 8; it++) {
      int u = t + 512 * it;
      int row = u >> 5, cc = u & 31;
      int hl = cc >> 4;
      size_t gb = ((size_t)(bq * 16 + (hl ? hB : hA)) * TSEQ + tpos0 + row) * 128 + (cc & 15) * 8;
      *(uint4*)(dst + gb) = *(const uint4*)(sC + row * 264 + cc * 8);
    }
  } else {
    // V stored transposed (B,H,D,T): stage as sC[d][tpos_local], then 16B stores along T
#pragma unroll
    for (int j = 0; j < 8; j++) {
      int d = wn + j * 16 + l16;
#pragma unroll
      for (int i = 0; i < 2; i++)
#pragma unroll
        for (int r = 0; r < 4; r++) {
          int col = rowbase + i * 16 + quad * 4 + r;
          sC[d * 136 + col] = f2b(acc[i][j][r]);
        }
    }
    __syncthreads();
#pragma unroll
    for (int it = 0; it < 8; it++) {
      int u = t + 512 * it;
      int dd = u >> 4, cc = u & 15;
      int hl = dd >> 7, dl = dd & 127;
      size_t gb = ((size_t)(bq * 16 + (hl ? hB : hA)) * 128 + dl) * TSEQ + tpos0 + cc * 8;
      *(uint4*)(Vtd + gb) = *(const uint4*)(sC + dd * 136 + cc * 8);
    }
  }
}

// ---------------- Flash attention v2 (unchanged) ----------------
// Pair-balanced causal schedule: block (pair, bh) handles q-tiles qA=pair, qB=31-pair
// (33 tile-computes per block, K/V tile at each kb loaded ONCE for both tiles).
// Double-buffered K/V in LDS; XOR-swizzled 16B-chunk placement kills the 16-way bank
// conflicts. LDS: 2*(8192+8192) + 4*16*72 = 74752 B -> 2 blocks/CU.
__global__ __launch_bounds__(256, 2) void attn_kernel(const unsigned short* __restrict__ Q,
                                                      const unsigned short* __restrict__ Kmat,
                                                      const unsigned short* __restrict__ Vt,
                                                      unsigned short* __restrict__ Ob) {
  __shared__ unsigned short smem[37376];
  const int pair = blockIdx.x, bh = blockIdx.y;
  const int qA = pair, qB = 31 - pair;
  const int t = threadIdx.x, lane = t & 63, w = t >> 6, quad = lane >> 4, l16 = lane & 15;
  const size_t base = (size_t)bh * TSEQ * 128;
  const unsigned short* Qp = Q + base;
  const unsigned short* Kp = Kmat + base;
  const unsigned short* Vp = Vt + base;
  unsigned short* myP = smem + 32768 + w * 1152;   // 16 x 72 per wave

  bf16x8 aqA[4], aqB[4];
  {
    int qrA = qA * 64 + w * 16 + l16;
    int qrB = qB * 64 + w * 16 + l16;
#pragma unroll
    for (int kk = 0; kk < 4; kk++) {
      aqA[kk] = *(const bf16x8*)(Qp + (size_t)qrA * 128 + kk * 32 + quad * 8);
      aqB[kk] = *(const bf16x8*)(Qp + (size_t)qrB * 128 + kk * 32 + quad * 8);
    }
  }
  const f32x4 z = {0.f, 0.f, 0.f, 0.f};
  f32x4 oA[8], oB[8];
  float mA[4], lA[4], mB[4], lB[4];
#pragma unroll
  for (int dt = 0; dt < 8; dt++) { oA[dt] = z; oB[dt] = z; }
#pragma unroll
  for (int r = 0; r < 4; r++) { mA[r] = -1e30f; lA[r] = 0.f; mB[r] = -1e30f; lB[r] = 0.f; }

  // swizzled K/V tile load: chunk c of row r lives at slot (c ^ (r&7))
  auto load_tiles = [&](int kb, int buf) {
    unsigned short* bK = smem + buf * 16384;
    unsigned short* bV = bK + 8192;
    const unsigned short* Kt = Kp + (size_t)kb * 64 * 128;
#pragma unroll
    for (int i2 = 0; i2 < 4; i2++) {
      int idx = t + 256 * i2;                       // LDS linear 16B-chunk
      int r = idx >> 4, cS = idx & 15;
      int c = cS ^ (r & 7);
      gload_lds16(Kt + r * 128 + c * 8, bK + idx * 8);
    }
#pragma unroll
    for (int i2 = 0; i2 < 4; i2++) {
      int idx = t + 256 * i2;
      int r = idx >> 3, cS = idx & 7;               // r = d index
      int c = cS ^ (r & 7);
      gload_lds16(Vp + (size_t)r * TSEQ + kb * 64 + c * 8, bV + idx * 8);
    }
  };

  auto process = [&](bf16x8 (&aq)[4], f32x4 (&o)[8], float (&mst)[4], float (&lst)[4],
                     int qb, int kb, const unsigned short* bK, const unsigned short* bV) {
    f32x4 S[4];
#pragma unroll
    for (int nt = 0; nt < 4; nt++) {
      f32x4 sacc = z;
#pragma unroll
      for (int kk = 0; kk < 4; kk++) {
        const unsigned short* p =
            bK + (nt * 16 + l16) * 128 + (((kk * 4 + quad) ^ (l16 & 7)) * 8);
        sacc = mfma16(aq[kk], *(const bf16x8*)p, sacc);
      }
      S[nt] = sacc;
    }
    if (kb == qb) {  // diagonal tile: mask key > q
      int qg = qb * 64 + w * 16 + quad * 4;
#pragma unroll
      for (int nt = 0; nt < 4; nt++) {
        int key = kb * 64 + nt * 16 + l16;
#pragma unroll
        for (int r = 0; r < 4; r++)
          if (key > qg + r) S[nt][r] = -1e30f;
      }
    }
    float alpha[4];
#pragma unroll
    for (int r = 0; r < 4; r++) {
      float mx = fmaxf(fmaxf(S[0][r], S[1][r]), fmaxf(S[2][r], S[3][r]));
      mx = fmaxf(mx, __shfl_xor(mx, 1, 64));
      mx = fmaxf(mx, __shfl_xor(mx, 2, 64));
      mx = fmaxf(mx, __shfl_xor(mx, 4, 64));
      mx = fmaxf(mx, __shfl_xor(mx, 8, 64));
      float mnew = fmaxf(mst[r], mx);
      alpha[r] = __expf(mst[r] - mnew);
      mst[r] = mnew;
    }
    float rs[4] = {0.f, 0.f, 0.f, 0.f};
#pragma unroll
    for (int nt = 0; nt < 4; nt++)
#pragma unroll
      for (int r = 0; r < 4; r++) {
        float p = __expf(S[nt][r] - mst[r]);
        S[nt][r] = p;
        rs[r] += p;
      }
#pragma unroll
    for (int r = 0; r < 4; r++) {
      float s4 = rs[r];
      s4 += __shfl_xor(s4, 1, 64);
      s4 += __shfl_xor(s4, 2, 64);
      s4 += __shfl_xor(s4, 4, 64);
      s4 += __shfl_xor(s4, 8, 64);
      lst[r] = lst[r] * alpha[r] + s4;
#pragma unroll
      for (int nt = 0; nt < 4; nt++)
        myP[(quad * 4 + r) * 72 + nt * 16 + l16] = f2b(S[nt][r]);
    }
#pragma unroll
    for (int dt = 0; dt < 8; dt++) {
      f32x4 ov = o[dt];
      ov[0] *= alpha[0]; ov[1] *= alpha[1]; ov[2] *= alpha[2]; ov[3] *= alpha[3];
      o[dt] = ov;
    }
#pragma unroll
    for (int kk = 0; kk < 2; kk++) {
      bf16x8 ap = *(const bf16x8*)(myP + l16 * 72 + kk * 32 + quad * 8);
#pragma unroll
      for (int dt = 0; dt < 8; dt++) {
        const unsigned short* p =
            bV + (dt * 16 + l16) * 64 + (((kk * 4 + quad) ^ (l16 & 7)) * 8);
        o[dt] = mfma16(ap, *(const bf16x8*)p, o[dt]);
      }
    }
  };

  load_tiles(0, 0);
#pragma unroll 1
  for (int kb = 0; kb <= qB; kb++) {
    __syncthreads();                      // drains loads for current buffer
    if (kb < qB) load_tiles(kb + 1, (kb + 1) & 1);  // prefetch overlaps compute below
    const unsigned short* bK = smem + (kb & 1) * 16384;
    const unsigned short* bV = bK + 8192;
    process(aqB, oB, mB, lB, qB, kb, bK, bV);
    if (kb <= qA) process(aqA, oA, mA, lA, qA, kb, bK, bV);
  }

  // epilogue: both tiles -> LDS (stride 136) -> coalesced 16B stores to Ob (b,t,h,d)
  __syncthreads();                        // all waves done reading K/V buffers
  unsigned short* sOA = smem;             // 64 x 136
  unsigned short* sOB = smem + 8704;      // 64 x 136
#pragma unroll
  for (int dt = 0; dt < 8; dt++)
#pragma unroll
    for (int r = 0; r < 4; r++) {
      int row = w * 16 + quad * 4 + r;
      sOA[row * 136 + dt * 16 + l16] = f2b(oA[dt][r] / lA[r]);
      sOB[row * 136 + dt * 16 + l16] = f2b(oB[dt][r] / lB[r]);
    }
  __syncthreads();
  const int b = bh >> 4, h = bh & 15;
#pragma unroll
  for (int it = 0; it < 4; it++) {
    int c = t + 256 * it;
    int row = c >> 4, off = (c & 15) * 8;
    uint4 va = *(const uint4*)(sOA + row * 136 + off);
    *(uint4*)(Ob + (size_t)(b * TSEQ + qA * 64 + row) * 2048 + h * 128 + off) = va;
    uint4 vb = *(const uint4*)(sOB + row * 136 + off);
    *(uint4*)(Ob + (size_t)(b * TSEQ + qB * 64 + row) * 2048 + h * 128 + off) = vb;
  }
}

// ---------------- GEMM2: out = Ob @ W_out, fp32 epilogue ----------------
// Grid 8x32 = 256 blocks at 1 block/CU = exactly 1.0 scheduling round.
__global__ __launch_bounds__(512, 2) void gemm_out_kernel(const unsigned short* __restrict__ Ob,
                                                          const unsigned short* __restrict__ Wot,
                                                          float* __restrict__ Cout) {
  __shared__ unsigned short smem[73728];  // 144 KB ring + merge buf
  f32x4 acc[4][8];
  const f32x4 z = {0.f, 0.f, 0.f, 0.f};
#pragma unroll
  for (int i = 0; i < 4; i++)
#pragma unroll
    for (int j = 0; j < 8; j++) acc[i][j] = z;

  const int bm = blockIdx.y * 128, bn = blockIdx.x * 256;
  gemm_core_256(Ob, Wot, 2048, bm, bn, smem, acc);

  const int t = threadIdx.x, lane = t & 63, w = t >> 6;
  const int wloc = w & 3;
  const int wm = (wloc >> 1) * 64, wn = (wloc & 1) * 128;
  const int rowbase = wm + (w >> 2) * 32;
  const int quad = lane >> 4, l16 = lane & 15;
#pragma unroll
  for (int i = 0; i < 2; i++)
#pragma unroll
    for (int j = 0; j < 8; j++)
#pragma unroll
      for (int r = 0; r < 4; r++) {
        int row = bm + rowbase + i * 16 + quad * 4 + r;
        int col = bn + wn + j * 16 + l16;
        Cout[(size_t)row * 2048 + col] = acc[i][j][r];
      }
}

// ---------------- launch ----------------
extern "C" void kernel_launch(void* const* d_in, const int* in_sizes, int n_in,
                              void* d_out, int out_size, void* d_ws, size_t ws_size,
                              hipStream_t stream) {
  (void)in_sizes; (void)n_in; (void)out_size; (void)ws_size;
  const float* x = (const float*)d_in[0];       // (2,2048,2048)
  const float* Wqkv = (const float*)d_in[1];    // (2048,6144)
  const float* Wout = (const float*)d_in[2];    // (2048,2048)
  float* out = (float*)d_out;                   // (2,2048,2048) fp32
  char* ws = (char*)d_ws;

  unsigned short* Xb  = (unsigned short*)(ws);               // 16 MB  (4096x2048 bf16)
  unsigned short* Wqt = (unsigned short*)(ws + 16777216);    // 24 MB  (6144x2048 bf16, W_qkv^T)
  unsigned short* Wot = (unsigned short*)(ws + 41943040);    // 8 MB   (2048x2048 bf16, W_out^T)
  unsigned short* Qd  = (unsigned short*)(ws + 50331648);    // 16 MB  (B,H,T,D)
  unsigned short* Kd  = (unsigned short*)(ws + 67108864);    // 16 MB  (B,H,T,D)
  unsigned short* Vtd = (unsigned short*)(ws + 83886080);    // 16 MB  (B,H,D,T)
  unsigned short* Obf = (unsigned short*)(ws + 100663296);   // 16 MB  (4096x2048 bf16)

  cast_bf16_kernel<<<8192, 256, 0, stream>>>(x, Xb);
  transpose_cast_kernel<<<dim3(96, 32), 256, 0, stream>>>(Wqkv, Wqt, 2048, 6144);
  transpose_cast_kernel<<<dim3(32, 32), 256, 0, stream>>>(Wout, Wot, 2048, 2048);
  gemm_qkv_rope<<<dim3(24, 32), 512, 0, stream>>>(Xb, Wqt, Qd, Kd, Vtd);
  attn_kernel<<<dim3(16, 32), 256, 0, stream>>>(Qd, Kd, Vtd, Obf);
  gemm_out_kernel<<<dim3(8, 32), 512, 0, stream>>>(Obf, Wot, out);
}

// Round 4
// 366.280 us; speedup vs baseline: 1.5081x; 1.0118x over previous
//
#include <hip/hip_runtime.h>
#include <stdint.h>

// Problem constants: B=2, T=2048, C=2048, H=16, D=128
#define TSEQ 2048

typedef __bf16 bf16x8 __attribute__((ext_vector_type(8)));
typedef float f32x4 __attribute__((ext_vector_type(4)));

typedef const __attribute__((address_space(1))) unsigned int* gas_u32;
typedef __attribute__((address_space(3))) unsigned int* las_u32;

__device__ __forceinline__ f32x4 mfma16(bf16x8 a, bf16x8 b, f32x4 c) {
  return __builtin_amdgcn_mfma_f32_16x16x32_bf16(a, b, c, 0, 0, 0);
}

// fp32 -> bf16 round-to-nearest-even (values are finite; no NaN path needed)
__device__ __forceinline__ unsigned short f2b(float f) {
  unsigned int u = __float_as_uint(f);
  u += 0x7fffu + ((u >> 16) & 1u);
  return (unsigned short)(u >> 16);
}

// async global->LDS, 16B per lane. LDS dest must be wave-uniform base + lane*16.
__device__ __forceinline__ void gload_lds16(const unsigned short* g, unsigned short* l) {
  __builtin_amdgcn_global_load_lds((gas_u32)(const void*)g, (las_u32)(void*)l, 16, 0, 0);
}

// ---------------- cast fp32 -> bf16 (vectorized, exact-size grid) ----------------
__global__ __launch_bounds__(256) void cast_bf16_kernel(const float* __restrict__ src,
                                                        unsigned short* __restrict__ dst) {
  size_t i = ((size_t)blockIdx.x * 256 + threadIdx.x) * 4;
  float4 v = *(const float4*)(src + i);
  ushort4 o;
  o.x = f2b(v.x); o.y = f2b(v.y); o.z = f2b(v.z); o.w = f2b(v.w);
  *(ushort4*)(dst + i) = o;
}

// ---------------- cast + transpose: src (R x Cc) fp32 -> dst (Cc x R) bf16 ----------------
__global__ __launch_bounds__(256) void transpose_cast_kernel(const float* __restrict__ src,
                                                             unsigned short* __restrict__ dst,
                                                             int R, int Cc) {
  __shared__ float tile[64][65];
  int cb = blockIdx.x * 64;
  int rb = blockIdx.y * 64;
  int t = threadIdx.x;
  int tr = t >> 4;          // 0..15
  int tc = (t & 15) * 4;    // 0..60
#pragma unroll
  for (int i = 0; i < 4; i++) {
    int r = tr + 16 * i;
    float4 v = *(const float4*)(src + (size_t)(rb + r) * Cc + cb + tc);
    tile[r][tc + 0] = v.x; tile[r][tc + 1] = v.y;
    tile[r][tc + 2] = v.z; tile[r][tc + 3] = v.w;
  }
  __syncthreads();
#pragma unroll
  for (int i = 0; i < 4; i++) {
    int r2 = tr + 16 * i;   // dst row = src col
    ushort4 o;
    o.x = f2b(tile[tc + 0][r2]);
    o.y = f2b(tile[tc + 1][r2]);
    o.z = f2b(tile[tc + 2][r2]);
    o.w = f2b(tile[tc + 3][r2]);
    *(ushort4*)(dst + (size_t)(cb + r2) * R + rb + tc) = o;
  }
}

// ---------------- GEMM core: 128x256 tile, BK=64, ring-of-3 LDS, counted vmcnt ----------------
// K-SPLIT wave decomposition: 8 waves = output grid 2(M)x2(N) x 2(K-halves).
// Wave w: wloc=w&3 -> (wm,wn) in {0,64}x{0,128}; ks=w>>2 -> K-half of each BK=64 tile.
// Per-wave output 64x128 partial (acc[4][8]); per K-tile: 12 ds_read_b128 (4A+8B) feed
// 32 MFMAs = 384 B per 16kFLOP MFMA. Partial accs of wave pairs (w, w^4) merged via LDS
// after the K-loop.
//
// PHASE DISCIPLINE (T3/m201 port; round-3 measured 42% MfmaUtil with a single barrier
// per K-tile because LLVM hoisted all 12 ds_reads together and waves stalled in
// lockstep): each K-tile = 4 quadrant phases, each
//   {ds_read subtile; stage-issue; s_waitcnt lgkmcnt(0); sched_barrier(0);
//    setprio(1) 8xMFMA setprio(0); s_barrier; sched_barrier(0)}
// (phase 3's trailing barrier merges with the next tile-top barrier). sched_barrier
// pins the schedule (rule #18); setprio now has role-split to arbitrate (T5/m218b).
//
// !! ALL acc indices compile-time constants (rule #20; round-2's runtime indexing
// demoted acc to scratch: WRITE_SIZE 49->540 MB, 2.2x slower).
//
// Ring invariants (unchanged, verified rounds 1-3):
//  - while computing tile t from slot t%3, the 6 global_load_lds for tile t+2 go into
//    slot (t-1)%3, whose reads are lgkm-drained in every wave's phases of iter t-1,
//    before the tile-top barrier of iter t -> write-after-read safe.
//  - tile-top "s_waitcnt vmcnt(6) lgkmcnt(0)" retires exactly tile t's 6 loads; tile
//    t+1's 6 stay in flight ACROSS the barrier. Last iter waits vmcnt(0).
//  - bank conflicts: 128B rows; 16B chunk q of row r lives at slot q ^ (r&7); stage
//    pre-swizzles the GLOBAL source (LDS dest linear), reads apply the same involution.
// After return: wave w owns tile rows [wm + (w>>2)*32, +32) x cols [wn, wn+128) in
// acc[0..1][0..7]. Core ends with merge sync; callers reusing sm must sync again.
__device__ __forceinline__ void gemm_core_256(const unsigned short* __restrict__ A,
                                              const unsigned short* __restrict__ Bt,
                                              int K, int bm, int bn,
                                              unsigned short* sm,
                                              f32x4 (&acc)[4][8]) {
  const int t = threadIdx.x;
  const int lane = t & 63, w = t >> 6;
  const int wloc = w & 3;
  const int wm = (wloc >> 1) * 64;       // 0 or 64
  const int wn = (wloc & 1) * 128;       // 0 or 128
  const int ks = w >> 2;                 // K-half of each BK=64 tile
  const int quad = lane >> 4, l16 = lane & 15;
  const int rsw = l16 & 7;               // == row&7 for all frag rows this lane touches
  const int ch = ((ks * 4 + quad) ^ rsw) * 8;  // swizzled chunk offset (shorts) in 64-short row

  // staging: thread handles LDS 16B-chunks {t, t+512(, t+1024, t+1536 for B)};
  // chunk u: row = u>>3, slot = u&7, global chunk = slot ^ (row&7). row+64 keeps row&7.
  const int srow = t >> 3;               // 0..63
  const int gch = (t & 7) ^ (srow & 7);
  const unsigned short* pA = A + (size_t)(bm + srow) * K + gch * 8;
  const unsigned short* pB = Bt + (size_t)(bn + srow) * K + gch * 8;
  const size_t K64 = (size_t)64 * K;

  auto stageA = [&](int k0, unsigned short* dstSlot) {
    gload_lds16(pA + k0, dstSlot + t * 8);
    gload_lds16(pA + K64 + k0, dstSlot + (t + 512) * 8);
  };
  auto stageB01 = [&](int k0, unsigned short* dstSlot) {
    unsigned short* tB = dstSlot + 8192;
    gload_lds16(pB + k0, tB + t * 8);
    gload_lds16(pB + K64 + k0, tB + (t + 512) * 8);
  };
  auto stageB23 = [&](int k0, unsigned short* dstSlot) {
    unsigned short* tB = dstSlot + 8192;
    gload_lds16(pB + 2 * K64 + k0, tB + (t + 1024) * 8);
    gload_lds16(pB + 3 * K64 + k0, tB + (t + 1536) * 8);
  };

  // prologue: stage tiles 0 and 1 (6 loads each)
  stageA(0, sm);          stageB01(0, sm);          stageB23(0, sm);
  stageA(64, sm + 24576); stageB01(64, sm + 24576); stageB23(64, sm + 24576);

  const int nIter = K >> 6;   // 32
  int scur = 0, sstg = 2;

#pragma unroll 1
  for (int it = 0; it < nIter; it++) {
    if (it + 1 < nIter)
      asm volatile("s_waitcnt vmcnt(6) lgkmcnt(0)" ::: "memory");
    else
      asm volatile("s_waitcnt vmcnt(0) lgkmcnt(0)" ::: "memory");
    __builtin_amdgcn_s_barrier();
    __builtin_amdgcn_sched_barrier(0);

    const unsigned short* sA = sm + scur * 24576;
    const unsigned short* sB = sA + 8192;
    unsigned short* tgt = sm + sstg * 24576;
    const bool doStage = (it + 2 < nIter);
    const int k2 = (it + 2) << 6;

    bf16x8 aF[4], bF[8];

    auto mm = [&](int jb) {   // 8 MFMAs; jb is always a literal -> static after inline
      __builtin_amdgcn_s_setprio(1);
#pragma unroll
      for (int i = 0; i < 4; i++)
#pragma unroll
        for (int j2 = 0; j2 < 2; j2++)
          acc[i][jb + j2] = mfma16(aF[i], bF[jb + j2], acc[i][jb + j2]);
      __builtin_amdgcn_s_setprio(0);
    };
    auto waitlgkm = [&]() {
      asm volatile("s_waitcnt lgkmcnt(0)" ::: "memory");
      __builtin_amdgcn_sched_barrier(0);
    };
    auto phasebar = [&]() {
      __builtin_amdgcn_s_barrier();
      __builtin_amdgcn_sched_barrier(0);
    };

    // ph0: readA(4) + readB[0..1]; stage A(t+2); mm(0)
#pragma unroll
    for (int i = 0; i < 4; i++)
      aF[i] = *(const bf16x8*)(sA + (wm + i * 16 + l16) * 64 + ch);
#pragma unroll
    for (int j = 0; j < 2; j++)
      bF[j] = *(const bf16x8*)(sB + (wn + j * 16 + l16) * 64 + ch);
    if (doStage) stageA(k2, tgt);
    waitlgkm();
    mm(0);
    phasebar();

    // ph1: readB[2..3]; stage B01; mm(2)
#pragma unroll
    for (int j = 2; j < 4; j++)
      bF[j] = *(const bf16x8*)(sB + (wn + j * 16 + l16) * 64 + ch);
    if (doStage) stageB01(k2, tgt);
    waitlgkm();
    mm(2);
    phasebar();

    // ph2: readB[4..5]; stage B23; mm(4)
#pragma unroll
    for (int j = 4; j < 6; j++)
      bF[j] = *(const bf16x8*)(sB + (wn + j * 16 + l16) * 64 + ch);
    if (doStage) stageB23(k2, tgt);
    waitlgkm();
    mm(4);
    phasebar();

    // ph3: readB[6..7]; mm(6)  (trailing barrier merges with next tile-top barrier)
#pragma unroll
    for (int j = 6; j < 8; j++)
      bF[j] = *(const bf16x8*)(sB + (wn + j * 16 + l16) * 64 + ch);
    waitlgkm();
    mm(6);

    scur = (scur == 2) ? 0 : scur + 1;
    sstg = (sstg == 2) ? 0 : sstg + 1;
  }
  __syncthreads();   // all ds_reads of ring done; mbuf below may overwrite slots

  // K-split merge: pair (w, w^4) shares (wm,wn); each gives away half its m-frags.
  // w<4 keeps m-frags 0..1 (rows wm..wm+31) and gives 2..3; w>=4 the reverse, then
  // canonicalizes its kept frags into slots 0..1. All indices STATIC (rule #20).
  // Layout per wave: 16 KB at mbuf + w*4096 floats, frag f=(i2*8+j) at f*256 + lane*4
  // (ds_write_b128 / ds_read_b128, lane*16B consecutive -> conflict-free).
  {
    float* mbuf = (float*)sm;
    float* wb = mbuf + w * 4096;
    const int lane4 = lane * 4;
    if (w < 4) {
#pragma unroll
      for (int i2 = 0; i2 < 2; i2++)
#pragma unroll
        for (int j = 0; j < 8; j++)
          *(f32x4*)(wb + (i2 * 8 + j) * 256 + lane4) = acc[2 + i2][j];
    } else {
#pragma unroll
      for (int i2 = 0; i2 < 2; i2++)
#pragma unroll
        for (int j = 0; j < 8; j++)
          *(f32x4*)(wb + (i2 * 8 + j) * 256 + lane4) = acc[i2][j];
    }
    __syncthreads();
    const float* pb = mbuf + (w ^ 4) * 4096;
    if (w < 4) {
#pragma unroll
      for (int i2 = 0; i2 < 2; i2++)
#pragma unroll
        for (int j = 0; j < 8; j++)
          acc[i2][j] += *(const f32x4*)(pb + (i2 * 8 + j) * 256 + lane4);
    } else {
#pragma unroll
      for (int i2 = 0; i2 < 2; i2++)
#pragma unroll
        for (int j = 0; j < 8; j++)
          acc[i2][j] = acc[2 + i2][j] + *(const f32x4*)(pb + (i2 * 8 + j) * 256 + lane4);
    }
  }
}

// ---------------- GEMM1: qkv = Xb @ Wqkv, fused RoPE epilogue ----------------
// blockIdx.x in [0,24): 256 cols = two adjacent (s,h) head chunks, same s.
// s=0:Q(+scale), 1:K, 2:V(->V^T). After the K-split core, wave w owns tile rows
// rowbase..rowbase+31 in acc[0..1][0..7] (canonicalized).
// Grid 24x32 = 768 blocks at 1 block/CU (144 KB LDS) = exactly 3.0 scheduling rounds.
__global__ __launch_bounds__(512, 2) void gemm_qkv_rope(const unsigned short* __restrict__ Xb,
                                                        const unsigned short* __restrict__ Wqt,
                                                        unsigned short* __restrict__ Qd,
                                                        unsigned short* __restrict__ Kd,
                                                        unsigned short* __restrict__ Vtd) {
  __shared__ unsigned short smem[73728];  // 144 KB: ring 3x48KB | merge buf | epilogue
  f32x4 acc[4][8];
  const f32x4 z = {0.f, 0.f, 0.f, 0.f};
#pragma unroll
  for (int i = 0; i < 4; i++)
#pragma unroll
    for (int j = 0; j < 8; j++) acc[i][j] = z;

  const int bm = blockIdx.y * 128;
  const int bn = blockIdx.x * 256;
  gemm_core_256(Xb, Wqt, 2048, bm, bn, smem, acc);

  const int c0 = blockIdx.x * 2;          // head-chunk pair
  const int s = c0 >> 4;
  const int hA = c0 & 15, hB = (c0 + 1) & 15;
  const int t = threadIdx.x, lane = t & 63, w = t >> 6;
  const int wloc = w & 3;
  const int wm = (wloc >> 1) * 64, wn = (wloc & 1) * 128;
  const int rowbase = wm + (w >> 2) * 32;
  const int quad = lane >> 4, l16 = lane & 15;
  const int bq = bm >> 11;                // batch index (tiles never straddle batches)
  const int tpos0 = bm & (TSEQ - 1);

  __syncthreads();                        // merge reads done; safe to reuse smem
  unsigned short* sC = smem;

  if (s < 2) {
    const float scl = (s == 0) ? 0.08838834764831845f : 1.0f;  // 1/sqrt(128) folded into Q
#pragma unroll
    for (int j = 0; j < 8; j++) {
      int d = wn + j * 16 + l16;
      int dh = d & 127;                                     // dim within head
      float invf = __expf(-(float)(dh >> 1) * 0.14391157f); // ln(10000)/64
#pragma unroll
      for (int i = 0; i < 2; i++) {
#pragma unroll
        for (int r = 0; r < 4; r++) {
          int row = rowbase + i * 16 + quad * 4 + r;   // tile-local tpos
          float ang = (float)(tpos0 + row) * invf;
          float sn, cs;
          __sincosf(ang, &sn, &cs);
          float v = acc[i][j][r];
          float p = __shfl_xor(v, 1, 64);  // partner column d^1 (adjacent lane)
          float outv = (d & 1) ? (v * cs + p * sn) : (v * cs - p * sn);
          sC[row * 264 + d] = f2b(outv * scl);
        }
      }
    }
    __syncthreads();
    unsigned short* dst = (s == 0) ? Qd : Kd;
#pragma unroll
    for (int it = 0; it < 8; it++) {
      int u = t + 512 * it;
      int row = u >> 5, cc = u & 31;
      int hl = cc >> 4;
      size_t gb = ((size_t)(bq * 16 + (hl ? hB : hA)) * TSEQ + tpos0 + row) * 128 + (cc & 15) * 8;
      *(uint4*)(dst + gb) = *(const uint4*)(sC + row * 264 + cc * 8);
    }
  } else {
    // V stored transposed (B,H,D,T): stage as sC[d][tpos_local], then 16B stores along T
#pragma unroll
    for (int j = 0; j < 8; j++) {
      int d = wn + j * 16 + l16;
#pragma unroll
      for (int i = 0; i < 2; i++)
#pragma unroll
        for (int r = 0; r < 4; r++) {
          int col = rowbase + i * 16 + quad * 4 + r;
          sC[d * 136 + col] = f2b(acc[i][j][r]);
        }
    }
    __syncthreads();
#pragma unroll
    for (int it = 0; it < 8; it++) {
      int u = t + 512 * it;
      int dd = u >> 4, cc = u & 15;
      int hl = dd >> 7, dl = dd & 127;
      size_t gb = ((size_t)(bq * 16 + (hl ? hB : hA)) * 128 + dl) * TSEQ + tpos0 + cc * 8;
      *(uint4*)(Vtd + gb) = *(const uint4*)(sC + dd * 136 + cc * 8);
    }
  }
}

// ---------------- Flash attention v2 (unchanged) ----------------
// Pair-balanced causal schedule: block (pair, bh) handles q-tiles qA=pair, qB=31-pair
// (33 tile-computes per block, K/V tile at each kb loaded ONCE for both tiles).
// Double-buffered K/V in LDS; XOR-swizzled 16B-chunk placement kills the 16-way bank
// conflicts. LDS: 2*(8192+8192) + 4*16*72 = 74752 B -> 2 blocks/CU.
__global__ __launch_bounds__(256, 2) void attn_kernel(const unsigned short* __restrict__ Q,
                                                      const unsigned short* __restrict__ Kmat,
                                                      const unsigned short* __restrict__ Vt,
                                                      unsigned short* __restrict__ Ob) {
  __shared__ unsigned short smem[37376];
  const int pair = blockIdx.x, bh = blockIdx.y;
  const int qA = pair, qB = 31 - pair;
  const int t = threadIdx.x, lane = t & 63, w = t >> 6, quad = lane >> 4, l16 = lane & 15;
  const size_t base = (size_t)bh * TSEQ * 128;
  const unsigned short* Qp = Q + base;
  const unsigned short* Kp = Kmat + base;
  const unsigned short* Vp = Vt + base;
  unsigned short* myP = smem + 32768 + w * 1152;   // 16 x 72 per wave

  bf16x8 aqA[4], aqB[4];
  {
    int qrA = qA * 64 + w * 16 + l16;
    int qrB = qB * 64 + w * 16 + l16;
#pragma unroll
    for (int kk = 0; kk < 4; kk++) {
      aqA[kk] = *(const bf16x8*)(Qp + (size_t)qrA * 128 + kk * 32 + quad * 8);
      aqB[kk] = *(const bf16x8*)(Qp + (size_t)qrB * 128 + kk * 32 + quad * 8);
    }
  }
  const f32x4 z = {0.f, 0.f, 0.f, 0.f};
  f32x4 oA[8], oB[8];
  float mA[4], lA[4], mB[4], lB[4];
#pragma unroll
  for (int dt = 0; dt < 8; dt++) { oA[dt] = z; oB[dt] = z; }
#pragma unroll
  for (int r = 0; r < 4; r++) { mA[r] = -1e30f; lA[r] = 0.f; mB[r] = -1e30f; lB[r] = 0.f; }

  // swizzled K/V tile load: chunk c of row r lives at slot (c ^ (r&7))
  auto load_tiles = [&](int kb, int buf) {
    unsigned short* bK = smem + buf * 16384;
    unsigned short* bV = bK + 8192;
    const unsigned short* Kt = Kp + (size_t)kb * 64 * 128;
#pragma unroll
    for (int i2 = 0; i2 < 4; i2++) {
      int idx = t + 256 * i2;                       // LDS linear 16B-chunk
      int r = idx >> 4, cS = idx & 15;
      int c = cS ^ (r & 7);
      gload_lds16(Kt + r * 128 + c * 8, bK + idx * 8);
    }
#pragma unroll
    for (int i2 = 0; i2 < 4; i2++) {
      int idx = t + 256 * i2;
      int r = idx >> 3, cS = idx & 7;               // r = d index
      int c = cS ^ (r & 7);
      gload_lds16(Vp + (size_t)r * TSEQ + kb * 64 + c * 8, bV + idx * 8);
    }
  };

  auto process = [&](bf16x8 (&aq)[4], f32x4 (&o)[8], float (&mst)[4], float (&lst)[4],
                     int qb, int kb, const unsigned short* bK, const unsigned short* bV) {
    f32x4 S[4];
#pragma unroll
    for (int nt = 0; nt < 4; nt++) {
      f32x4 sacc = z;
#pragma unroll
      for (int kk = 0; kk < 4; kk++) {
        const unsigned short* p =
            bK + (nt * 16 + l16) * 128 + (((kk * 4 + quad) ^ (l16 & 7)) * 8);
        sacc = mfma16(aq[kk], *(const bf16x8*)p, sacc);
      }
      S[nt] = sacc;
    }
    if (kb == qb) {  // diagonal tile: mask key > q
      int qg = qb * 64 + w * 16 + quad * 4;
#pragma unroll
      for (int nt = 0; nt < 4; nt++) {
        int key = kb * 64 + nt * 16 + l16;
#pragma unroll
        for (int r = 0; r < 4; r++)
          if (key > qg + r) S[nt][r] = -1e30f;
      }
    }
    float alpha[4];
#pragma unroll
    for (int r = 0; r < 4; r++) {
      float mx = fmaxf(fmaxf(S[0][r], S[1][r]), fmaxf(S[2][r], S[3][r]));
      mx = fmaxf(mx, __shfl_xor(mx, 1, 64));
      mx = fmaxf(mx, __shfl_xor(mx, 2, 64));
      mx = fmaxf(mx, __shfl_xor(mx, 4, 64));
      mx = fmaxf(mx, __shfl_xor(mx, 8, 64));
      float mnew = fmaxf(mst[r], mx);
      alpha[r] = __expf(mst[r] - mnew);
      mst[r] = mnew;
    }
    float rs[4] = {0.f, 0.f, 0.f, 0.f};
#pragma unroll
    for (int nt = 0; nt < 4; nt++)
#pragma unroll
      for (int r = 0; r < 4; r++) {
        float p = __expf(S[nt][r] - mst[r]);
        S[nt][r] = p;
        rs[r] += p;
      }
#pragma unroll
    for (int r = 0; r < 4; r++) {
      float s4 = rs[r];
      s4 += __shfl_xor(s4, 1, 64);
      s4 += __shfl_xor(s4, 2, 64);
      s4 += __shfl_xor(s4, 4, 64);
      s4 += __shfl_xor(s4, 8, 64);
      lst[r] = lst[r] * alpha[r] + s4;
#pragma unroll
      for (int nt = 0; nt < 4; nt++)
        myP[(quad * 4 + r) * 72 + nt * 16 + l16] = f2b(S[nt][r]);
    }
#pragma unroll
    for (int dt = 0; dt < 8; dt++) {
      f32x4 ov = o[dt];
      ov[0] *= alpha[0]; ov[1] *= alpha[1]; ov[2] *= alpha[2]; ov[3] *= alpha[3];
      o[dt] = ov;
    }
#pragma unroll
    for (int kk = 0; kk < 2; kk++) {
      bf16x8 ap = *(const bf16x8*)(myP + l16 * 72 + kk * 32 + quad * 8);
#pragma unroll
      for (int dt = 0; dt < 8; dt++) {
        const unsigned short* p =
            bV + (dt * 16 + l16) * 64 + (((kk * 4 + quad) ^ (l16 & 7)) * 8);
        o[dt] = mfma16(ap, *(const bf16x8*)p, o[dt]);
      }
    }
  };

  load_tiles(0, 0);
#pragma unroll 1
  for (int kb = 0; kb <= qB; kb++) {
    __syncthreads();                      // drains loads for current buffer
    if (kb < qB) load_tiles(kb + 1, (kb + 1) & 1);  // prefetch overlaps compute below
    const unsigned short* bK = smem + (kb & 1) * 16384;
    const unsigned short* bV = bK + 8192;
    process(aqB, oB, mB, lB, qB, kb, bK, bV);
    if (kb <= qA) process(aqA, oA, mA, lA, qA, kb, bK, bV);
  }

  // epilogue: both tiles -> LDS (stride 136) -> coalesced 16B stores to Ob (b,t,h,d)
  __syncthreads();                        // all waves done reading K/V buffers
  unsigned short* sOA = smem;             // 64 x 136
  unsigned short* sOB = smem + 8704;      // 64 x 136
#pragma unroll
  for (int dt = 0; dt < 8; dt++)
#pragma unroll
    for (int r = 0; r < 4; r++) {
      int row = w * 16 + quad * 4 + r;
      sOA[row * 136 + dt * 16 + l16] = f2b(oA[dt][r] / lA[r]);
      sOB[row * 136 + dt * 16 + l16] = f2b(oB[dt][r] / lB[r]);
    }
  __syncthreads();
  const int b = bh >> 4, h = bh & 15;
#pragma unroll
  for (int it = 0; it < 4; it++) {
    int c = t + 256 * it;
    int row = c >> 4, off = (c & 15) * 8;
    uint4 va = *(const uint4*)(sOA + row * 136 + off);
    *(uint4*)(Ob + (size_t)(b * TSEQ + qA * 64 + row) * 2048 + h * 128 + off) = va;
    uint4 vb = *(const uint4*)(sOB + row * 136 + off);
    *(uint4*)(Ob + (size_t)(b * TSEQ + qB * 64 + row) * 2048 + h * 128 + off) = vb;
  }
}

// ---------------- GEMM2: out = Ob @ W_out, fp32 epilogue ----------------
// Grid 8x32 = 256 blocks at 1 block/CU = exactly 1.0 scheduling round.
__global__ __launch_bounds__(512, 2) void gemm_out_kernel(const unsigned short* __restrict__ Ob,
                                                          const unsigned short* __restrict__ Wot,
                                                          float* __restrict__ Cout) {
  __shared__ unsigned short smem[73728];  // 144 KB ring + merge buf
  f32x4 acc[4][8];
  const f32x4 z = {0.f, 0.f, 0.f, 0.f};
#pragma unroll
  for (int i = 0; i < 4; i++)
#pragma unroll
    for (int j = 0; j < 8; j++) acc[i][j] = z;

  const int bm = blockIdx.y * 128, bn = blockIdx.x * 256;
  gemm_core_256(Ob, Wot, 2048, bm, bn, smem, acc);

  const int t = threadIdx.x, lane = t & 63, w = t >> 6;
  const int wloc = w & 3;
  const int wm = (wloc >> 1) * 64, wn = (wloc & 1) * 128;
  const int rowbase = wm + (w >> 2) * 32;
  const int quad = lane >> 4, l16 = lane & 15;
#pragma unroll
  for (int i = 0; i < 2; i++)
#pragma unroll
    for (int j = 0; j < 8; j++)
#pragma unroll
      for (int r = 0; r < 4; r++) {
        int row = bm + rowbase + i * 16 + quad * 4 + r;
        int col = bn + wn + j * 16 + l16;
        Cout[(size_t)row * 2048 + col] = acc[i][j][r];
      }
}

// ---------------- launch ----------------
extern "C" void kernel_launch(void* const* d_in, const int* in_sizes, int n_in,
                              void* d_out, int out_size, void* d_ws, size_t ws_size,
                              hipStream_t stream) {
  (void)in_sizes; (void)n_in; (void)out_size; (void)ws_size;
  const float* x = (const float*)d_in[0];       // (2,2048,2048)
  const float* Wqkv = (const float*)d_in[1];    // (2048,6144)
  const float* Wout = (const float*)d_in[2];    // (2048,2048)
  float* out = (float*)d_out;                   // (2,2048,2048) fp32
  char* ws = (char*)d_ws;

  unsigned short* Xb  = (unsigned short*)(ws);               // 16 MB  (4096x2048 bf16)
  unsigned short* Wqt = (unsigned short*)(ws + 16777216);    // 24 MB  (6144x2048 bf16, W_qkv^T)
  unsigned short* Wot = (unsigned short*)(ws + 41943040);    // 8 MB   (2048x2048 bf16, W_out^T)
  unsigned short* Qd  = (unsigned short*)(ws + 50331648);    // 16 MB  (B,H,T,D)
  unsigned short* Kd  = (unsigned short*)(ws + 67108864);    // 16 MB  (B,H,T,D)
  unsigned short* Vtd = (unsigned short*)(ws + 83886080);    // 16 MB  (B,H,D,T)
  unsigned short* Obf = (unsigned short*)(ws + 100663296);   // 16 MB  (4096x2048 bf16)

  cast_bf16_kernel<<<8192, 256, 0, stream>>>(x, Xb);
  transpose_cast_kernel<<<dim3(96, 32), 256, 0, stream>>>(Wqkv, Wqt, 2048, 6144);
  transpose_cast_kernel<<<dim3(32, 32), 256, 0, stream>>>(Wout, Wot, 2048, 2048);
  gemm_qkv_rope<<<dim3(24, 32), 512, 0, stream>>>(Xb, Wqt, Qd, Kd, Vtd);
  attn_kernel<<<dim3(16, 32), 256, 0, stream>>>(Qd, Kd, Vtd, Obf);
  gemm_out_kernel<<<dim3(8, 32), 512, 0, stream>>>(Obf, Wot, out);
}